// Round 7
// baseline (151.604 us; speedup 1.0000x reference)
//
#include <hip/hip_runtime.h>

#define WI 512
#define HI 512
#define WO 2048
#define HO 2048
#define NIMG 8
#define CCH 3
#define EPS 1e-8f
#define PLANE (HI * WI)

#define SEG  512      // output px per block (segment of a row)
#define TPB  128      // threads per block
#define PXT  4        // px per thread (SEG/TPB), strided by TPB
#define MAXR 516      // staged texel capacity (<= 512 needed + slack)

struct ImgUni {
    float wy0, wy1, my;   // y-blend weights (validity-premultiplied), my = wy0+wy1
    int   y0o, y1o;       // clamped src row offsets (premult by WI)
    int   t0, t1;         // staged texel subrange [t0, t1] (global x indices)
};

// Per-(image, row, segment) uniforms. Returns false if m == 0 for every px in
// the segment (exact skip: y-weights zero, or x-range misses (-1, WI)).
__device__ __forceinline__ bool img_uniforms(const float4 P, const float ys,
                                             const int wo0, ImgUni& u) {
    // y side (reference op order)
    const float gy  = P.z * ys + P.w;
    const float iy  = ((gy + 1.0f) * (float)HI - 1.0f) * 0.5f;
    const float y0f = floorf(iy);
    const float fy1 = iy - y0f;
    const float fy0 = 1.0f - fy1;
    const float y1f = y0f + 1.0f;
    const float v0  = (y0f >= 0.0f && y0f < (float)HI) ? 1.0f : 0.0f;
    const float v1  = (y1f >= 0.0f && y1f < (float)HI) ? 1.0f : 0.0f;
    u.wy0 = fy0 * v0;
    u.wy1 = fy1 * v1;
    u.my  = u.wy0 + u.wy1;
    u.y0o = (int)fminf(fmaxf(y0f, 0.0f), (float)(HI - 1)) * WI;
    u.y1o = (int)fminf(fmaxf(y1f, 0.0f), (float)(HI - 1)) * WI;
    if (!(u.my > 0.0f)) return false;

    // x side: segment endpoint ix values (a > 0 always => monotone increasing)
    const float a  = P.x, tx = P.y;
    const float xsf = (2.0f * (float)wo0 + 1.0f) / (float)WO - 1.0f;
    const float xsl = (2.0f * (float)(wo0 + SEG - 1) + 1.0f) / (float)WO - 1.0f;
    const float ixf = ((a * xsf + tx + 1.0f) * (float)WI - 1.0f) * 0.5f;
    const float ixl = ((a * xsl + tx + 1.0f) * (float)WI - 1.0f) * 0.5f;
    if (ixl <= -1.0f || ixf >= (float)WI) return false;   // all wx == 0
    u.t0 = (int)fminf(fmaxf(floorf(ixf), 0.0f), (float)(WI - 1));
    u.t1 = (int)fminf(fmaxf(floorf(ixl) + 1.0f, 0.0f), (float)(WI - 1));
    return true;
}

// ===========================================================================
// v7: one block per (row, 512-px segment). 8192 blocks -> 32/CU backfill.
// Per covered image (block-uniform): stage y-collapsed texel subrange into
// LDS (coalesced b32), double-buffered (1 barrier/image); per-px x-blend with
// lane-consecutive px mapping (bank-broadcast LDS reads for slope < 2).
// ===========================================================================
__launch_bounds__(TPB)
__global__ void diffcomp_fused7(const float* __restrict__ src,
                                const float* __restrict__ bg,
                                const float* __restrict__ coor,
                                float* __restrict__ out) {
    __shared__ float  cs[2][CCH][MAXR];   // y-collapsed subrange, 2 slots
    __shared__ float4 prm[NIMG];

    const int tid = threadIdx.x;
    const int b   = blockIdx.x;
    const int row = b >> 2;
    const int wo0 = (b & 3) * SEG;

    if (tid < NIMG) {
        const float cx  = coor[tid * 4 + 0];
        const float cy  = coor[tid * 4 + 1];
        const float cw  = coor[tid * 4 + 2];
        const float chh = coor[tid * 4 + 3];
        const float x = (1.0f / (1.0f + expf(-cx))) * (float)WO;
        const float y = (1.0f / (1.0f + expf(-cy))) * (float)HO;
        const float w = (1.0f / (1.0f + expf(-cw))) * (float)WO;
        const float h = (1.0f / (1.0f + expf(-chh))) * (float)HO;
        const float a  = (float)WO / (w + EPS);
        const float tx = (2.0f / (float)WO) * ((float)WO * 0.5f - x) * a;
        const float bb = (float)HO / (h + EPS);
        const float ty = (2.0f / (float)HO) * ((float)HO * 0.5f - y) * bb;
        prm[tid] = make_float4(a, tx, bb, ty);
    }
    __syncthreads();

    const float ys = (2.0f * (float)row + 1.0f) / (float)HO - 1.0f;

    // Coverage mask (uniform across block).
    unsigned cov = 0u;
#pragma unroll
    for (int n = 0; n < NIMG; n++) {
        ImgUni u;
        if (img_uniforms(prm[n], ys, wo0, u)) cov |= (1u << n);
    }

    // Accumulators: PXT px per thread, strided by TPB (lane-consecutive).
    const int base = row * WO + wo0 + tid;
    float acc[CCH][PXT];
#pragma unroll
    for (int c = 0; c < CCH; c++)
#pragma unroll
        for (int p = 0; p < PXT; p++)
            acc[c][p] = bg[c * HO * WO + base + p * TPB];

    if (cov) {
        // ---- stage helper (block-uniform n) ----
        auto stage = [&](int slot, int n) {
            ImgUni u;
            img_uniforms(prm[n], ys, wo0, u);
            const float* ib = src + n * (CCH * PLANE);
            const int R = u.t1 - u.t0 + 1;
            for (int i = tid; i < R; i += TPB) {
#pragma unroll
                for (int c = 0; c < CCH; c++) {
                    const float r0 = ib[c * PLANE + u.y0o + u.t0 + i];
                    const float r1 = ib[c * PLANE + u.y1o + u.t0 + i];
                    cs[slot][c][i] = r0 * u.wy0 + r1 * u.wy1;
                }
            }
        };

        // ---- blend helper ----
        auto blend = [&](int slot, int n) {
            ImgUni u;
            img_uniforms(prm[n], ys, wo0, u);
            const float a  = prm[n].x;
            const float tx = prm[n].y;
            const int lim = u.t1 - u.t0;
#pragma unroll
            for (int p = 0; p < PXT; p++) {
                const int wo = wo0 + p * TPB + tid;
                const float xs  = (2.0f * (float)wo + 1.0f) / (float)WO - 1.0f;
                const float gx  = a * xs + tx;
                const float ix  = ((gx + 1.0f) * (float)WI - 1.0f) * 0.5f;
                const float x0f = floorf(ix);
                const float fx1 = ix - x0f;
                const float fx0 = 1.0f - fx1;
                const float x1f = x0f + 1.0f;
                const float v0  = (x0f >= 0.0f && x0f < (float)WI) ? 1.0f : 0.0f;
                const float v1  = (x1f >= 0.0f && x1f < (float)WI) ? 1.0f : 0.0f;
                const float wx0 = fx0 * v0;
                const float wx1 = fx1 * v1;
                int x0r = (int)fminf(fmaxf(x0f, 0.0f), (float)(WI - 1)) - u.t0;
                int x1r = (int)fminf(fmaxf(x1f, 0.0f), (float)(WI - 1)) - u.t0;
                // safety clamp into staged range (no-op when weight > 0)
                x0r = min(max(x0r, 0), lim);
                x1r = min(max(x1r, 0), lim);
                const float m  = u.my * (wx0 + wx1);
                const float om = 1.0f - m;
#pragma unroll
                for (int c = 0; c < CCH; c++) {
                    const float q0 = cs[slot][c][x0r];
                    const float q1 = cs[slot][c][x1r];
                    const float sc = q0 * wx0 + q1 * wx1;
                    acc[c][p] = acc[c][p] * om + sc * m;
                }
            }
        };

        int cur = (int)__builtin_ctz(cov);
        unsigned rest = cov & (cov - 1u);

        stage(0, cur);
        __syncthreads();

        int s = 0;
        while (true) {
            const int nxt = rest ? (int)__builtin_ctz(rest) : -1;
            if (nxt >= 0) stage(s ^ 1, nxt);
            blend(s, cur);
            __syncthreads();
            if (nxt < 0) break;
            cur = nxt;
            rest &= rest - 1u;
            s ^= 1;
        }
    }

#pragma unroll
    for (int c = 0; c < CCH; c++)
#pragma unroll
        for (int p = 0; p < PXT; p++)
            out[c * HO * WO + base + p * TPB] = acc[c][p];
}

extern "C" void kernel_launch(void* const* d_in, const int* in_sizes, int n_in,
                              void* d_out, int out_size, void* d_ws, size_t ws_size,
                              hipStream_t stream) {
    const float* src  = (const float*)d_in[0];   // [8,3,512,512]
    const float* bg   = (const float*)d_in[1];   // [1,3,2048,2048]
    const float* coor = (const float*)d_in[2];   // [8,4]
    float* out = (float*)d_out;                  // [1,3,2048,2048]
    (void)d_ws; (void)ws_size;

    hipLaunchKernelGGL(diffcomp_fused7, dim3(HO * 4), dim3(TPB), 0, stream,
                       src, bg, coor, out);
}

// Round 8
// 134.332 us; speedup vs baseline: 1.1286x; 1.1286x over previous
//
#include <hip/hip_runtime.h>

#define WI 512
#define HI 512
#define WO 2048
#define HO 2048
#define NIMG 8
#define CCH 3
#define EPS 1e-8f
#define PLANE (HI * WI)

#define TPB  256      // threads per block
#define SEG  1024     // output px per block (half row)
#define PXT  4        // px per thread, strided by TPB
#define CAP  520      // LDS texels per channel slot (512 + float4 slack)

struct SState {       // per-(image,row,segment) uniform state
    float wy0, wy1, my;
    int   t0a, R, lim;
    int   valid;
};

// y/x uniforms for image-param P at row ys, segment [wo0, wo0+SEG).
// valid==0 -> m==0 for every px of the segment (exact skip).
__device__ __forceinline__ SState calc_state(const float4 P, const float ys,
                                             const int wo0) {
    SState st; st.valid = 0; st.wy0 = st.wy1 = st.my = 0.0f;
    st.t0a = 0; st.R = 0; st.lim = 0;
    const float gy  = P.z * ys + P.w;
    const float iy  = ((gy + 1.0f) * (float)HI - 1.0f) * 0.5f;
    const float y0f = floorf(iy);
    const float fy1 = iy - y0f;
    const float fy0 = 1.0f - fy1;
    const float y1f = y0f + 1.0f;
    const float v0  = (y0f >= 0.0f && y0f < (float)HI) ? 1.0f : 0.0f;
    const float v1  = (y1f >= 0.0f && y1f < (float)HI) ? 1.0f : 0.0f;
    st.wy0 = fy0 * v0;
    st.wy1 = fy1 * v1;
    st.my  = st.wy0 + st.wy1;
    if (!(st.my > 0.0f)) return st;

    const float a  = P.x, tx = P.y;
    const float xsf = (2.0f * (float)wo0 + 1.0f) / (float)WO - 1.0f;
    const float xsl = (2.0f * (float)(wo0 + SEG - 1) + 1.0f) / (float)WO - 1.0f;
    const float ixf = ((a * xsf + tx + 1.0f) * (float)WI - 1.0f) * 0.5f;
    const float ixl = ((a * xsl + tx + 1.0f) * (float)WI - 1.0f) * 0.5f;
    if (ixl <= -1.0f || ixf >= (float)WI) return st;    // all wx == 0

    const int t0 = (int)fminf(fmaxf(floorf(ixf), 0.0f), (float)(WI - 1));
    const int t1 = (int)fminf(fmaxf(floorf(ixl) + 1.0f, 0.0f), (float)(WI - 1));
    st.t0a = t0 & ~3;                                   // float4 alignment
    int R = (t1 - st.t0a + 4) & ~3;                     // round up to x4
    if (R > WI - st.t0a) R = WI - st.t0a;               // stay inside the row
    st.R   = R;
    st.lim = t1 - st.t0a;
    st.valid = 1;
    return st;
}

// ===========================================================================
// v8: one block per (row, half-row segment). Software-pipelined per image:
//   load(next)->regs ; commit(cur)->LDS ; barrier ; blend(cur)
// so next image's global loads stay in flight across barrier+blend.
// Staging is float4-vectorized on the aligned subrange; blend uses
// lane-consecutive px mapping (bank-broadcast LDS reads). 1 barrier/image.
// ===========================================================================
__launch_bounds__(TPB)
__global__ void diffcomp_v8(const float* __restrict__ src,
                            const float* __restrict__ bg,
                            const float* __restrict__ coor,
                            float* __restrict__ out) {
    __shared__ float  cs[2][CCH][CAP];
    __shared__ float4 prm[NIMG];

    const int tid = threadIdx.x;
    const int b   = blockIdx.x;
    const int row = b >> 1;
    const int wo0 = (b & 1) << 10;

    if (tid < NIMG) {
        const float cx  = coor[tid * 4 + 0];
        const float cy  = coor[tid * 4 + 1];
        const float cw  = coor[tid * 4 + 2];
        const float chh = coor[tid * 4 + 3];
        const float x = (1.0f / (1.0f + expf(-cx))) * (float)WO;
        const float y = (1.0f / (1.0f + expf(-cy))) * (float)HO;
        const float w = (1.0f / (1.0f + expf(-cw))) * (float)WO;
        const float h = (1.0f / (1.0f + expf(-chh))) * (float)HO;
        const float a  = (float)WO / (w + EPS);
        const float tx = (2.0f / (float)WO) * ((float)WO * 0.5f - x) * a;
        const float bb = (float)HO / (h + EPS);
        const float ty = (2.0f / (float)HO) * ((float)HO * 0.5f - y) * bb;
        prm[tid] = make_float4(a, tx, bb, ty);
    }
    __syncthreads();

    const float ys = (2.0f * (float)row + 1.0f) / (float)HO - 1.0f;

    // Coverage mask (uniform across the block).
    unsigned cov = 0u;
#pragma unroll
    for (int n = 0; n < NIMG; n++) {
        if (calc_state(prm[n], ys, wo0).valid) cov |= (1u << n);
    }

    // Per-px xs values (image-independent), hoisted out of the image loop.
    float xsv[PXT];
#pragma unroll
    for (int p = 0; p < PXT; p++) {
        const int wo = wo0 + p * TPB + tid;
        xsv[p] = (2.0f * (float)wo + 1.0f) / (float)WO - 1.0f;
    }

    // Accumulators (strided, lane-consecutive, coalesced).
    const int base = row * WO + wo0 + tid;
    float acc[CCH][PXT];
#pragma unroll
    for (int c = 0; c < CCH; c++)
#pragma unroll
        for (int p = 0; p < PXT; p++)
            acc[c][p] = bg[c * HO * WO + base + p * TPB];

    if (cov) {
        // ---- register-stage loaders ----
        float4 A0[CCH], A1[CCH], B0[CCH], B1[CCH];
        SState stA, stB;

        auto load_img = [&](int n, SState& st, float4* r0, float4* r1) {
            st = calc_state(prm[n], ys, wo0);
            const int xo = tid << 2;
            if (xo < st.R) {
                const float* ib = src + n * (CCH * PLANE) + st.t0a + xo;
                const float gy  = prm[n].z * ys + prm[n].w;
                const float iy  = ((gy + 1.0f) * (float)HI - 1.0f) * 0.5f;
                const float y0f = floorf(iy);
                const int y0o = (int)fminf(fmaxf(y0f, 0.0f), (float)(HI - 1)) * WI;
                const int y1o = (int)fminf(fmaxf(y0f + 1.0f, 0.0f), (float)(HI - 1)) * WI;
#pragma unroll
                for (int c = 0; c < CCH; c++) {
                    r0[c] = *(const float4*)(ib + c * PLANE + y0o);
                    r1[c] = *(const float4*)(ib + c * PLANE + y1o);
                }
            }
        };

        auto commit_img = [&](int slot, const SState& st,
                              const float4* r0, const float4* r1) {
            const int xo = tid << 2;
            if (xo < st.R) {
#pragma unroll
                for (int c = 0; c < CCH; c++) {
                    float4 rc;
                    rc.x = r0[c].x * st.wy0 + r1[c].x * st.wy1;
                    rc.y = r0[c].y * st.wy0 + r1[c].y * st.wy1;
                    rc.z = r0[c].z * st.wy0 + r1[c].z * st.wy1;
                    rc.w = r0[c].w * st.wy0 + r1[c].w * st.wy1;
                    *(float4*)&cs[slot][c][xo] = rc;
                }
            }
        };

        auto blend_img = [&](int slot, int n, const SState& st) {
            const float a  = prm[n].x;
            const float tx = prm[n].y;
#pragma unroll
            for (int p = 0; p < PXT; p++) {
                const float gx  = a * xsv[p] + tx;
                const float ix  = ((gx + 1.0f) * (float)WI - 1.0f) * 0.5f;
                const float x0f = floorf(ix);
                const float fx1 = ix - x0f;
                const float fx0 = 1.0f - fx1;
                const float x1f = x0f + 1.0f;
                const float v0  = (x0f >= 0.0f && x0f < (float)WI) ? 1.0f : 0.0f;
                const float v1  = (x1f >= 0.0f && x1f < (float)WI) ? 1.0f : 0.0f;
                const float wx0 = fx0 * v0;
                const float wx1 = fx1 * v1;
                int x0r = (int)fminf(fmaxf(x0f, 0.0f), (float)(WI - 1)) - st.t0a;
                int x1r = (int)fminf(fmaxf(x1f, 0.0f), (float)(WI - 1)) - st.t0a;
                x0r = min(max(x0r, 0), st.lim);
                x1r = min(max(x1r, 0), st.lim);
                const float m  = st.my * (wx0 + wx1);
                const float om = 1.0f - m;
#pragma unroll
                for (int c = 0; c < CCH; c++) {
                    const float q0 = cs[slot][c][x0r];
                    const float q1 = cs[slot][c][x1r];
                    const float sc = q0 * wx0 + q1 * wx1;
                    acc[c][p] = acc[c][p] * om + sc * m;
                }
            }
        };

        int cur = (int)__builtin_ctz(cov);
        unsigned rest = cov & (cov - 1u);

        load_img(cur, stA, A0, A1);
        int s = 0;
        while (true) {
            const int nxt = rest ? (int)__builtin_ctz(rest) : -1;
            if (nxt >= 0) load_img(nxt, stB, B0, B1);   // in flight across blend
            commit_img(s, stA, A0, A1);
            __syncthreads();
            blend_img(s, cur, stA);
            if (nxt < 0) break;
            cur = nxt;
            rest &= rest - 1u;
            stA = stB;
#pragma unroll
            for (int c = 0; c < CCH; c++) { A0[c] = B0[c]; A1[c] = B1[c]; }
            s ^= 1;
        }
    }

#pragma unroll
    for (int c = 0; c < CCH; c++)
#pragma unroll
        for (int p = 0; p < PXT; p++)
            out[c * HO * WO + base + p * TPB] = acc[c][p];
}

extern "C" void kernel_launch(void* const* d_in, const int* in_sizes, int n_in,
                              void* d_out, int out_size, void* d_ws, size_t ws_size,
                              hipStream_t stream) {
    const float* src  = (const float*)d_in[0];   // [8,3,512,512]
    const float* bg   = (const float*)d_in[1];   // [1,3,2048,2048]
    const float* coor = (const float*)d_in[2];   // [8,4]
    float* out = (float*)d_out;                  // [1,3,2048,2048]
    (void)d_ws; (void)ws_size;

    hipLaunchKernelGGL(diffcomp_v8, dim3(HO * (WO / SEG)), dim3(TPB), 0, stream,
                       src, bg, coor, out);
}